// Round 4
// baseline (315.003 us; speedup 1.0000x reference)
//
#include <hip/hip_runtime.h>
#include <hip/hip_bf16.h>
#include <cstdint>

// Problem sizes (fixed by reference setup_inputs)
#define B_SZ 8192
#define F_SZ 4096
#define D_SZ 1024
#define K_SZ 2048  // 2*D : A = [x^2 | x], W = [inv2 | -2*mu*inv2]

typedef __bf16 bf16x8 __attribute__((ext_vector_type(8)));
typedef float f32x4 __attribute__((ext_vector_type(4)));     // MFMA acc
typedef float fvec4 __attribute__((ext_vector_type(4)));
typedef unsigned short u16x4 __attribute__((ext_vector_type(4)));

// round-to-nearest-even fp32 -> bf16 bits
__device__ __forceinline__ unsigned short f2bf(float f) {
    union { float f; unsigned u; } c; c.f = f;
    unsigned r = c.u + 0x7fff + ((c.u >> 16) & 1);
    return (unsigned short)(r >> 16);
}

// async global->LDS, 16 B per lane; LDS dest = wave-uniform base + lane*16
__device__ __forceinline__ void async16(const void* g, void* l) {
    __builtin_amdgcn_global_load_lds(
        (__attribute__((address_space(1))) void*)g,
        (__attribute__((address_space(3))) void*)l, 16, 0, 0);
}

// ---------------------------------------------------------------------------
// prep: UNCHANGED (byte-identical numerics). Not in rocprof top-5 => < 142 us.
// The constant ~157 us of non-gemm time across all rounds is unattributed
// (prep + harness restore dispatches); once gemm < prep it surfaces.
// ---------------------------------------------------------------------------
__global__ __launch_bounds__(256) void prep(const float* __restrict__ x,
                                            const float* __restrict__ mu,
                                            const float* __restrict__ sd,
                                            unsigned short* __restrict__ A,
                                            unsigned short* __restrict__ W,
                                            float* __restrict__ nmm) {
    const int tid = threadIdx.x;
    if (blockIdx.x < 4096) {
        const size_t o0 = (size_t)blockIdx.x * 2048 + tid * 4;
        fvec4 v0 = *(const fvec4*)(x + o0);
        fvec4 v1 = *(const fvec4*)(x + o0 + 1024);
        #pragma unroll
        for (int h = 0; h < 2; ++h) {
            fvec4 v = h ? v1 : v0;
            size_t oo = o0 + h * 1024;
            size_t b = oo >> 10;
            int d = (int)(oo & 1023);
            u16x4 xx, xs;
            xx.x = f2bf(v.x * v.x); xx.y = f2bf(v.y * v.y);
            xx.z = f2bf(v.z * v.z); xx.w = f2bf(v.w * v.w);
            xs.x = f2bf(v.x); xs.y = f2bf(v.y);
            xs.z = f2bf(v.z); xs.w = f2bf(v.w);
            *(u16x4*)(A + b * K_SZ + d) = xx;
            *(u16x4*)(A + b * K_SZ + 1024 + d) = xs;
        }
    } else {
        const int f = blockIdx.x - 4096;
        const int d = tid * 4;
        size_t off = (size_t)f * D_SZ + d;
        fvec4 m = *(const fvec4*)(mu + off);
        fvec4 s = *(const fvec4*)(sd + off);
        float i0 = 1.0f / (s.x * s.x), i1 = 1.0f / (s.y * s.y);
        float i2 = 1.0f / (s.z * s.z), i3 = 1.0f / (s.w * s.w);
        u16x4 wi, wm;
        wi.x = f2bf(i0); wi.y = f2bf(i1); wi.z = f2bf(i2); wi.w = f2bf(i3);
        wm.x = f2bf(-2.0f * m.x * i0); wm.y = f2bf(-2.0f * m.y * i1);
        wm.z = f2bf(-2.0f * m.z * i2); wm.w = f2bf(-2.0f * m.w * i3);
        size_t wb = (size_t)f * K_SZ + d;
        *(u16x4*)(W + wb) = wi;
        *(u16x4*)(W + wb + 1024) = wm;
        float mm = m.x * m.x * i0 + m.y * m.y * i1 + m.z * m.z * i2 + m.w * m.w * i3;
        #pragma unroll
        for (int o = 32; o > 0; o >>= 1) mm += __shfl_down(mm, o, 64);
        __shared__ float red[4];
        if ((tid & 63) == 0) red[tid >> 6] = mm;
        __syncthreads();
        if (tid == 0) nmm[f] = -0.5f * (red[0] + red[1] + red[2] + red[3]);
    }
}

// ---------------------------------------------------------------------------
// GEMM: out[b,f] = -0.5 * (A @ W^T)[b,f] + nmm[f]
// 256x256 tile, BK=64, 8 waves (2M x 4N), per-wave 128x64 out.
//
// ROUND-4: CROSS-PHASE REGISTER PIPELINE. During phase p, issue the ds_reads
// for phase p+1's fragments into the alternate named set (afA/afB, bfA/bfB;
// all statically indexed). MFMA_p consumes data read a full phase earlier,
// so LDS latency+service runs under the MFMA shadow. Counted lgkmcnt(R)
// (R = reads just issued) before each MFMA cluster guarantees the previous
// phase's reads landed; sched_barrier(0) fences pin the order (rule #18).
// Per-lane LDS/global addresses hoisted out of the loop (VALU cut).
// Bijective XCD swizzle: 512 wgs = 8 XCDs x 64; each XCD gets an 8x8 block.
//
// Steady-state phase table (iter = tiles T@buf0 ph1-4, T+1@buf1 ph5-8):
//  ph  MFMA(B,A,I0) on        pre-read (into set)        stage            vm
//  1   bfA,afA,0  (b0,k0)     afB<-A[4:8](b0,k0)         T+1.k0 -> b1     4
//  2   bfA,afB,4  (b0,k0)     bfB<-B(b0,k1) afA<-A[0:4]  --               -
//  3   bfB,afA,0  (b0,k1)     afB<-A[4:8](b0,k1)         T+1.k1 -> b1     4
//  4   bfB,afB,4  (b0,k1)     bfA<-B(b1,k0) afA<-A[0:4]  --               -
//  5-8: same pattern on b1, staging T+2 -> b0.
//
// VMCNT LEDGER (odd phases issue 4 loads; vmcnt(4)@odd-end = own 4 remain,
// prior odd phase's 4 drained; drain-own -> barrier -> cross-wave read):
//   ph4 pre-reads (b1,k0): staged ph1, guaranteed ph3-end  OK
//   ph6 pre-reads (b1,k1): staged ph3, guaranteed ph5-end  OK
//   ph8 pre-reads (b0,k0,T+2): staged ph5, guaranteed ph7-end  OK
//   next-ph2 pre-reads (b0,k1,T+2): staged ph7, guaranteed next-ph1-end  OK
// Register WAR: sets alternate so each set is written only after its last
// MFMA use (checked per phase). LDS WAR: restage of a region >= 3 phases
// after its last ds_read. Peeled last iter: no T+2 staging; vm0@ph5 covers
// (b1,k1); ph8 skips pre-read, lgkmcnt(0).
// Prologue: stage T0.k0+T0.k1 (8 loads), vmcnt(4) lands k0, barrier,
// pre-read bfA/afA(b0,k0) -> ph1's lgkmcnt(4) drains them.
// Accumulation order per output = ascending 32-wide K chunks (numerics
// identical to all previous rounds).
// ---------------------------------------------------------------------------
__global__ __launch_bounds__(512, 2) void gemm_bt(const unsigned short* __restrict__ A,
                                                  const unsigned short* __restrict__ W,
                                                  const float* __restrict__ nmm,
                                                  float* __restrict__ out) {
    __shared__ __align__(16) unsigned short sA[2][2][256 * 32];
    __shared__ __align__(16) unsigned short sB[2][2][256 * 32];

    const int tid  = threadIdx.x;
    const int wave = tid >> 6;
    const int lane = tid & 63;
    const int r16  = lane & 15;
    const int quad = lane >> 4;
    const int wmB  = (wave >> 2) * 128;     // wave m-offset in 256 tile
    const int wnB  = (wave & 3) * 64;       // wave n-offset in 256 tile

    // XCD-aware swizzle: id%8 = XCD; give each XCD an 8x8 block of tiles.
    // S = (id&7)*64 + id/8 ; x=S>>6 (=XCD), c=S&63
    // nIdx = (x&1)*8 + (c&7)  in [0,16) ; mIdx = (x>>1)*8 + (c>>3) in [0,32)
    const int id = blockIdx.x;
    const int Ssw = ((id & 7) << 6) | (id >> 3);
    const int xsw = Ssw >> 6, csw = Ssw & 63;
    const int tileN = ((((xsw & 1) << 3) | (csw & 7))) << 8;
    const int tileM = ((((xsw >> 1) << 3) | (csw >> 3))) << 8;

    // ---- hoisted staging addresses ----
    const int srow   = tid >> 2;            // 0..127
    const int schunk = tid & 3;
    const int gc = (schunk ^ ((srow >> 1) & 3)) << 3;   // (srow+128)>>1 has same &3
    const unsigned short* gA0 = A + (size_t)(tileM + srow)       * K_SZ + gc;
    const unsigned short* gA1 = A + (size_t)(tileM + 128 + srow) * K_SZ + gc;
    const unsigned short* gW0 = W + (size_t)(tileN + srow)       * K_SZ + gc;
    const unsigned short* gW1 = W + (size_t)(tileN + 128 + srow) * K_SZ + gc;
    const int wdst = wave * 512;            // shorts; lane*16B appended by HW

    // ---- hoisted LDS read byte-offsets (within one [256*32] block) ----
    int aOff[8], bOff[4];
    #pragma unroll
    for (int i = 0; i < 8; ++i) {
        int row = wmB + i * 16 + r16;
        aOff[i] = row * 64 + (((quad ^ (row >> 1)) & 3) << 4);
    }
    #pragma unroll
    for (int j = 0; j < 4; ++j) {
        int row = wnB + j * 16 + r16;
        bOff[j] = row * 64 + (((quad ^ (row >> 1)) & 3) << 4);
    }

    const f32x4 vzero = {0.f, 0.f, 0.f, 0.f};
    f32x4 acc[8][4];
    #pragma unroll
    for (int i = 0; i < 8; ++i)
        #pragma unroll
        for (int j = 0; j < 4; ++j) acc[i][j] = vzero;

    bf16x8 afA[4], afB[4], bfA[4], bfB[4];

#define BARW() __builtin_amdgcn_s_barrier()
#define SBAR() __builtin_amdgcn_sched_barrier(0)
#define LGK4() asm volatile("s_waitcnt lgkmcnt(4)" ::: "memory")
#define LGK8() asm volatile("s_waitcnt lgkmcnt(8)" ::: "memory")
#define LGK0() asm volatile("s_waitcnt lgkmcnt(0)" ::: "memory")
#define VM4()  asm volatile("s_waitcnt vmcnt(4)" ::: "memory")
#define VM0()  asm volatile("s_waitcnt vmcnt(0)" ::: "memory")

// stage one K-half of BOTH matrices (4 global_load_lds)
#define STAGE4(DB, KK, KT)                                                   \
    { const size_t ko_ = (size_t)((KT) * 64 + (KK) * 32);                    \
      async16(gA0 + ko_, &sA[DB][KK][0] + wdst);                             \
      async16(gA1 + ko_, &sA[DB][KK][0] + 4096 + wdst);                      \
      async16(gW0 + ko_, &sB[DB][KK][0] + wdst);                             \
      async16(gW1 + ko_, &sB[DB][KK][0] + 4096 + wdst); }

#define RD_A4(DST, I0, DB, KK)                                               \
    { _Pragma("unroll")                                                      \
      for (int i_ = 0; i_ < 4; ++i_)                                         \
          DST[i_] = *(const bf16x8*)((const char*)&sA[DB][KK][0] +           \
                                     aOff[(I0) + i_]); }

#define RD_B4(DST, DB, KK)                                                   \
    { _Pragma("unroll")                                                      \
      for (int j_ = 0; j_ < 4; ++j_)                                         \
          DST[j_] = *(const bf16x8*)((const char*)&sB[DB][KK][0] +           \
                                     bOff[j_]); }

#define MM16(BF, AF, I0)                                                     \
    __builtin_amdgcn_s_setprio(1);                                          \
    { _Pragma("unroll")                                                      \
      for (int i_ = 0; i_ < 4; ++i_)                                         \
          _Pragma("unroll")                                                  \
          for (int j_ = 0; j_ < 4; ++j_)                                     \
              acc[(I0) + i_][j_] = __builtin_amdgcn_mfma_f32_16x16x32_bf16(  \
                  AF[i_], BF[j_], acc[(I0) + i_][j_], 0, 0, 0); }            \
    __builtin_amdgcn_s_setprio(0);

#define ITER(T, LAST)                                                        \
    /*ph1*/ RD_A4(afB, 4, 0, 0) STAGE4(1, 0, (T) + 1)                        \
            SBAR(); LGK4(); SBAR(); MM16(bfA, afA, 0) VM4(); BARW();         \
    /*ph2*/ RD_B4(bfB, 0, 1) RD_A4(afA, 0, 0, 1)                             \
            SBAR(); LGK8(); SBAR(); MM16(bfA, afB, 4) BARW();                \
    /*ph3*/ RD_A4(afB, 4, 0, 1) STAGE4(1, 1, (T) + 1)                        \
            SBAR(); LGK4(); SBAR(); MM16(bfB, afA, 0) VM4(); BARW();         \
    /*ph4*/ RD_B4(bfA, 1, 0) RD_A4(afA, 0, 1, 0)                             \
            SBAR(); LGK8(); SBAR(); MM16(bfB, afB, 4) BARW();                \
    /*ph5*/ RD_A4(afB, 4, 1, 0)                                              \
            if (!(LAST)) { STAGE4(0, 0, (T) + 2) }                           \
            SBAR(); LGK4(); SBAR(); MM16(bfA, afA, 0)                        \
            if (LAST) { VM0(); } else { VM4(); } BARW();                     \
    /*ph6*/ RD_B4(bfB, 1, 1) RD_A4(afA, 0, 1, 1)                             \
            SBAR(); LGK8(); SBAR(); MM16(bfA, afB, 4) BARW();                \
    /*ph7*/ RD_A4(afB, 4, 1, 1)                                              \
            if (!(LAST)) { STAGE4(0, 1, (T) + 2) }                           \
            SBAR(); LGK4(); SBAR(); MM16(bfB, afA, 0)                        \
            if (!(LAST)) { VM4(); } BARW();                                  \
    /*ph8*/ if (!(LAST)) { RD_B4(bfA, 0, 0) RD_A4(afA, 0, 0, 0) }            \
            SBAR(); if (LAST) { LGK0(); } else { LGK8(); } SBAR();           \
            MM16(bfB, afB, 4) BARW();

    // prologue: stage tile0 (both K-halves) into buf0; land k0; pre-read
    // the first fragment sets so ph1 can MFMA immediately.
    STAGE4(0, 0, 0)
    STAGE4(0, 1, 0)
    VM4(); BARW();
    RD_B4(bfA, 0, 0)
    RD_A4(afA, 0, 0, 0)

    #pragma unroll 1
    for (int X = 0; X < 15; ++X) {
        const int T = 2 * X;
        ITER(T, 0)
    }
    {
        ITER(30, 1)
    }

#undef ITER

    // epilogue: C/D layout col=lane&15 (N/W side), row=quad*4+reg (M/A side)
    int   fc[4];
    float cj[4];
    #pragma unroll
    for (int j = 0; j < 4; ++j) {
        fc[j] = tileN + wnB + j * 16 + r16;
        cj[j] = nmm[fc[j]];
    }
    #pragma unroll
    for (int i = 0; i < 8; ++i) {
        int mbase = tileM + wmB + i * 16 + quad * 4;
        #pragma unroll
        for (int r = 0; r < 4; ++r) {
            float* orow = out + (size_t)(mbase + r) * F_SZ;
            #pragma unroll
            for (int j = 0; j < 4; ++j)
                orow[fc[j]] = -0.5f * acc[i][j][r] + cj[j];
        }
    }
}

extern "C" void kernel_launch(void* const* d_in, const int* in_sizes, int n_in,
                              void* d_out, int out_size, void* d_ws, size_t ws_size,
                              hipStream_t stream) {
    const float* x  = (const float*)d_in[0];
    const float* mu = (const float*)d_in[1];
    const float* sd = (const float*)d_in[2];
    float* out = (float*)d_out;

    // workspace: A (8192x2048 bf16, 33.5 MB) | W (4096x2048 bf16, 16.8 MB) | nmm (16 KB)
    unsigned short* A = (unsigned short*)d_ws;
    unsigned short* W = A + (size_t)B_SZ * K_SZ;
    float* nmm = (float*)(W + (size_t)F_SZ * K_SZ);

    prep<<<8192, 256, 0, stream>>>(x, mu, sd, A, W, nmm);
    gemm_bt<<<512, 512, 0, stream>>>(A, W, nmm, out);
}